// Round 7
// baseline (191.073 us; speedup 1.0000x reference)
//
#include <hip/hip_runtime.h>
#include <hip/hip_bf16.h>

// CondConv: B=32, CIN=128, COUT=256, K=3, E=8, H=W=64 -> out [32,256,62,62] fp32
// Pipeline: nhwc(+pool partials) -> route(reduce+softmax) -> combine(bf16 cw)
//           -> implicit-GEMM MFMA conv: block 128x160, 4 waves (2Mx2N),
//           A staged in LDS (dbuf 2x16KB), B loaded DIRECT global->VGPR
//           (cacheline-clean gather, L2/L1 tap reuse), 1 barrier + counted
//           vmcnt per iter, 2 blocks/CU co-resident, full K-unroll.

#define CC_B    32
#define CC_CIN  128
#define CC_COUT 256
#define CC_NP   3844   // 62*62
#define CC_NT   18     // K-tiles: 9 taps x 2 cin-halves of 64

typedef __attribute__((ext_vector_type(8))) short bf16x8;
typedef __attribute__((ext_vector_type(4))) float f32x4;

// ------------------------------------------------- NHWC cast + pool partials
__global__ void cc_nhwc(const float* __restrict__ x, __hip_bfloat16* __restrict__ xn,
                        float* __restrict__ psum) {
    const int b = blockIdx.x >> 6, y = blockIdx.x & 63;   // 2048 blocks
    __shared__ float lds[64 * 129];                        // [x][cin], +1 pad
    __shared__ float sred[256];
    const int t = threadIdx.x;                             // 256
    const float* src = x + (size_t)b * CC_CIN * 4096 + y * 64;
#pragma unroll
    for (int i = 0; i < 32; ++i) {
        const int idx = i * 256 + t;
        const int cin = idx >> 6, xx = idx & 63;
        lds[xx * 129 + cin] = src[(size_t)cin * 4096 + xx];
    }
    __syncthreads();
    __hip_bfloat16* dst = xn + ((size_t)b * 4096 + y * 64) * CC_CIN;
#pragma unroll
    for (int j = 0; j < 4; ++j) {
        const int cidx = j * 256 + t;                      // 1024 chunks of 8 cin
        const int xx = cidx >> 4, c8 = (cidx & 15) * 8;
        union { __hip_bfloat16 h[8]; uint4 v; } u;
#pragma unroll
        for (int jj = 0; jj < 8; ++jj) u.h[jj] = __float2bfloat16(lds[xx * 129 + c8 + jj]);
        *reinterpret_cast<uint4*>(dst + (size_t)xx * CC_CIN + c8) = u.v;
    }
    // pool partial: sum over the 64 x's of this row
    const int cin = t & 127, xh = (t >> 7) * 32;
    float s = 0.f;
#pragma unroll
    for (int xx = 0; xx < 32; ++xx) s += lds[(xh + xx) * 129 + cin];
    sred[t] = s;
    __syncthreads();
    if (t < 128) psum[((size_t)b * 64 + y) * CC_CIN + t] = sred[t] + sred[t + 128];
}

// ------------------------------------------------- route: reduce + softmax --
__global__ void cc_route(const float* __restrict__ psum,
                         const float* __restrict__ rw_w,
                         const float* __restrict__ rw_b,
                         float* __restrict__ rweights) {
    const int b = blockIdx.x, c = threadIdx.x;             // 32 blocks x 128
    __shared__ float pl[128];
    __shared__ float lg[8];
    const float* p = psum + (size_t)b * 64 * CC_CIN + c;
    float s = 0.f;
#pragma unroll 8
    for (int y = 0; y < 64; ++y) s += p[(size_t)y * CC_CIN];
    pl[c] = s * (1.f / 4096.f);
    __syncthreads();
    if (c < 8) {
        const float* w = rw_w + c * CC_CIN;
        float a = rw_b[c];
#pragma unroll 8
        for (int i = 0; i < CC_CIN; ++i) a += pl[i] * w[i];
        lg[c] = a;
    }
    __syncthreads();
    if (c == 0) {
        float m = lg[0];
#pragma unroll
        for (int e = 1; e < 8; ++e) m = fmaxf(m, lg[e]);
        float ex[8], sm = 0.f;
#pragma unroll
        for (int e = 0; e < 8; ++e) { ex[e] = __expf(lg[e] - m); sm += ex[e]; }
#pragma unroll
        for (int e = 0; e < 8; ++e) rweights[b * 8 + e] = ex[e] / sm;
    }
}

// -------------------------------------------------------------- combine -----
// cw[b][t9][cout][cin] (bf16) = sum_e rw[b][e] * EW[e][cout][cin][ky][kx]
__global__ void cc_combine(const float* __restrict__ ew,
                           const float* __restrict__ rw,
                           __hip_bfloat16* __restrict__ cw) {
    const int t9 = blockIdx.x >> 8;            // 0..8
    const int cout = blockIdx.x & 255;
    const int cin = threadIdx.x;               // 128 threads
    __shared__ float rws[256];
    rws[cin] = rw[cin];
    rws[cin + 128] = rw[cin + 128];
    __syncthreads();
    float wv[8];
    const size_t base = ((size_t)cout * CC_CIN + cin) * 9 + t9;
#pragma unroll
    for (int e = 0; e < 8; ++e) wv[e] = ew[base + (size_t)e * (CC_COUT * CC_CIN * 9)];
#pragma unroll 4
    for (int b = 0; b < CC_B; ++b) {
        float acc = 0.f;
#pragma unroll
        for (int e = 0; e < 8; ++e) acc += rws[b * 8 + e] * wv[e];
        cw[(((size_t)b * 9 + t9) * CC_COUT + cout) * CC_CIN + cin] = __float2bfloat16(acc);
    }
}

// ----------------------------------------------------------------- conv -----
__device__ __forceinline__ void gload_lds16(const void* g, void* l) {
    __builtin_amdgcn_global_load_lds(
        (const __attribute__((address_space(1))) unsigned int*)g,
        (__attribute__((address_space(3))) unsigned int*)l, 16, 0, 0);
}

// grid 1600, block 256 (4 waves, 2M x 2N). Tile BM=128 couts x BN=160 pos,
// BK=64; per-wave 64x80 (40 MFMA/iter). A: LDS dbuf 2x16KB (swizzled rows);
// B: direct global->VGPR gather, double-buffered registers by unroll parity.
// Loop invariant entering iter t: VM queue = [Astage(t) 4, Bload(t) 10].
//   vmcnt(10) -> A(t) in LDS ; barrier ; Astage(t+1) [other buffer, its
//   readers retired last iter] ; ds_af x8 ; Bload(t+1) x10 ; vmcnt(14)
//   [retires B(t) and A(t) FIFO] ; lgkm(0) ; 40 MFMA.
// One barrier/iter, ordering-safe. Swizzle: slot s of 128B row r holds source
// chunk s^(r&7) (linear global_load_lds dest, pre-swizzled per-lane source).
__global__ __launch_bounds__(256, 2) void cc_conv(
    const __hip_bfloat16* __restrict__ xn,   // [B][64][64][128]
    const __hip_bfloat16* __restrict__ cw,   // [B][9][256][128]
    float* __restrict__ out)                 // [B][256][3844]
{
    __shared__ __align__(16) char smem[32768];   // A dbuf 2x16KB
    // ---- XCD-aware decode (bijective over 1600 = 8 xcd x 4 b x 25 nt x 2 mt)
    const int l   = blockIdx.x;
    const int xcd = l & 7, li = l >> 3;          // li in [0,200)
    const int b   = 4 * xcd + li / 50;
    const int r2  = li % 50;
    const int nt  = r2 >> 1, mt = r2 & 1;
    const int m0  = mt * 128;
    const int n0  = nt * 160;

    const int tid = threadIdx.x;
    const int wid = tid >> 6, lane = tid & 63;   // wid 0..3
    const int waveM = wid >> 1, waveN = wid & 1;

    f32x4 acc[4][5];
#pragma unroll
    for (int i = 0; i < 4; ++i)
#pragma unroll
        for (int j = 0; j < 5; ++j) acc[i][j] = (f32x4){0.f, 0.f, 0.f, 0.f};

    const int gsw = (lane & 7) ^ (lane >> 3);    // staging source-chunk swizzle
    int laOff[4];
#pragma unroll
    for (int i = 0; i < 4; ++i) {                // A rows: wid*32 + i*8 + l>>3
        const int row = wid * 32 + i * 8 + (lane >> 3);
        laOff[i] = (m0 + row) * CC_CIN + gsw * 8;
    }

    const __hip_bfloat16* cwb = cw + (size_t)b * 9 * CC_COUT * CC_CIN;
    const __hip_bfloat16* xnb = xn + (size_t)b * 4096 * CC_CIN;

    auto stageA = [&](int t) {
        const int t9 = t >> 1;
        const int aoff = t9 * (CC_COUT * CC_CIN) + (t & 1) * 64;
        char* Ab = smem + (t & 1) * 16384 + wid * 4096;
#pragma unroll
        for (int i = 0; i < 4; ++i)
            gload_lds16(cwb + aoff + laOff[i], Ab + i * 1024);
    };

    const int rl = lane & 15, q = lane >> 4;

    // per-lane B pixel offsets (elements), one per nf; includes q*8 k-chunk
    int pixq[5];
#pragma unroll
    for (int nf = 0; nf < 5; ++nf) {
        int p = n0 + waveN * 80 + nf * 16 + rl;
        if (p > CC_NP - 1) p = CC_NP - 1;        // tail clamp (dup, masked at store)
        const int oy = p / 62, ox = p - oy * 62;
        pixq[nf] = (oy * 64 + ox) * CC_CIN + q * 8;
    }

    bf16x8 bfr[2][10];
    auto loadB = [&](int t) {
        const int t9 = t >> 1;
        const int ky = (t9 * 11) >> 5;           // t9/3 for t9<9
        const int kx = t9 - ky * 3;
        const int kd = (ky * 64 + kx) * CC_CIN + (t & 1) * 64;
#pragma unroll
        for (int nf = 0; nf < 5; ++nf)
#pragma unroll
            for (int kk = 0; kk < 2; ++kk)
                bfr[t & 1][nf * 2 + kk] =
                    *(const bf16x8*)(xnb + pixq[nf] + kd + kk * 32);
    };

    // prologue: establish invariant [A(0) 4, B(0) 10]
    stageA(0);
    loadB(0);

#pragma unroll
    for (int t = 0; t < CC_NT; ++t) {
        const char* Ab = smem + (t & 1) * 16384;

        // ---- A(t) landed in LDS (retire own 4 stage issues), then sync
        asm volatile("s_waitcnt vmcnt(10)" ::: "memory");
        asm volatile("s_barrier" ::: "memory");

        // ---- stage A(t+1) into the other buffer (readers retired last iter)
        if (t + 1 < CC_NT) stageA(t + 1);

        // ---- A fragment reads from LDS
        bf16x8 af[8];
#pragma unroll
        for (int mf = 0; mf < 4; ++mf)
#pragma unroll
            for (int kk = 0; kk < 2; ++kk) {
                const int r = waveM * 64 + mf * 16 + rl;
                af[mf * 2 + kk] = *(const bf16x8*)(Ab + r * 128 + (((kk * 4 + q) ^ (r & 7)) * 16));
            }

        // ---- prefetch B(t+1) into the other register set
        if (t + 1 < CC_NT) loadB(t + 1);

        // ---- B(t) (and A(t+1)-order FIFO) retired; af ready
        if (t < CC_NT - 1) asm volatile("s_waitcnt vmcnt(14)" ::: "memory");
        else               asm volatile("s_waitcnt vmcnt(0)" ::: "memory");
        asm volatile("s_waitcnt lgkmcnt(0)" ::: "memory");

        __builtin_amdgcn_s_setprio(1);
#pragma unroll
        for (int kk = 0; kk < 2; ++kk)
#pragma unroll
            for (int mf = 0; mf < 4; ++mf)
#pragma unroll
                for (int nf = 0; nf < 5; ++nf)
                    acc[mf][nf] = __builtin_amdgcn_mfma_f32_16x16x32_bf16(
                        af[mf * 2 + kk], bfr[t & 1][nf * 2 + kk], acc[mf][nf], 0, 0, 0);
        __builtin_amdgcn_s_setprio(0);
    }

    // epilogue: C/D map col=lane&15 (p), row=(lane>>4)*4+j (cout)
    const int q4 = (lane >> 4) * 4;
#pragma unroll
    for (int mf = 0; mf < 4; ++mf) {
        const int crow = m0 + waveM * 64 + mf * 16 + q4;
#pragma unroll
        for (int nf = 0; nf < 5; ++nf) {
            const int p = n0 + waveN * 80 + nf * 16 + (lane & 15);
            if (p < CC_NP) {
                const size_t ob = ((size_t)b * CC_COUT + crow) * CC_NP + p;
#pragma unroll
                for (int j = 0; j < 4; ++j) out[ob + (size_t)j * CC_NP] = acc[mf][nf][j];
            }
        }
    }
}

// ---------------------------------------------------------------- launch ----
extern "C" void kernel_launch(void* const* d_in, const int* in_sizes, int n_in,
                              void* d_out, int out_size, void* d_ws, size_t ws_size,
                              hipStream_t stream) {
    const float* x   = (const float*)d_in[0];
    const float* ew  = (const float*)d_in[1];
    const float* rww = (const float*)d_in[2];
    const float* rwb = (const float*)d_in[3];
    float* out = (float*)d_out;
    char* ws = (char*)d_ws;

    __hip_bfloat16* xnhwc = (__hip_bfloat16*)ws;                    // 33,554,432 B
    __hip_bfloat16* cwcmb = (__hip_bfloat16*)(ws + 33554432);       // 18,874,368 B
    float* psum   = (float*)(ws + 52428800);                        //  1,048,576 B
    float* rwts   = (float*)(ws + 53493760);                        //      1,024 B

    cc_nhwc<<<dim3(CC_B * 64), dim3(256), 0, stream>>>(x, xnhwc, psum);
    cc_route<<<dim3(CC_B), dim3(128), 0, stream>>>(psum, rww, rwb, rwts);
    cc_combine<<<dim3(9 * CC_COUT), dim3(128), 0, stream>>>(ew, rwts, cwcmb);
    cc_conv<<<dim3(1600), dim3(256), 0, stream>>>(xnhwc, cwcmb, out);
}

// Round 8
// 127.137 us; speedup vs baseline: 1.5029x; 1.5029x over previous
//
#include <hip/hip_runtime.h>
#include <hip/hip_bf16.h>

// CondConv: B=32, CIN=128, COUT=256, K=3, E=8, H=W=64 -> out [32,256,62,62] fp32
// Pipeline: nhwc->k-plane-packed xnt[b][cin/8][y][x][8] (+pool partials) ->
//           route -> combine(bf16 cw) -> implicit-GEMM MFMA conv:
//           A staged in LDS (dbuf 2x16KB, swizzled), B loaded DIRECT
//           global->VGPR **coalesced** (16 consecutive pixels x 16B per
//           16-lane group), 1 barrier + counted vmcnt per iter, 2 blocks/CU.

#define CC_B    32
#define CC_CIN  128
#define CC_COUT 256
#define CC_NP   3844   // 62*62
#define CC_NT   18     // K-tiles: h(2 cin-halves) outer x 9 taps inner

typedef __attribute__((ext_vector_type(8))) short bf16x8;
typedef __attribute__((ext_vector_type(4))) float f32x4;

// --------------------------------- k-plane-packed cast + pool partials -----
// xnt[b][k8][y][x][8] bf16, k8 = cin/8 (16 planes of 64KB elems)
__global__ void cc_nhwc(const float* __restrict__ x, __hip_bfloat16* __restrict__ xnt,
                        float* __restrict__ psum) {
    const int b = blockIdx.x >> 6, y = blockIdx.x & 63;   // 2048 blocks
    __shared__ float lds[64 * 129];                        // [x][cin], +1 pad
    __shared__ float sred[256];
    const int t = threadIdx.x;                             // 256
    const float* src = x + (size_t)b * CC_CIN * 4096 + y * 64;
#pragma unroll
    for (int i = 0; i < 32; ++i) {
        const int idx = i * 256 + t;
        const int cin = idx >> 6, xx = idx & 63;
        lds[xx * 129 + cin] = src[(size_t)cin * 4096 + xx];
    }
    __syncthreads();
#pragma unroll
    for (int j = 0; j < 4; ++j) {
        const int cidx = j * 256 + t;                      // 1024 chunks of 8 cin
        const int k8 = cidx >> 6, xx = cidx & 63;          // consecutive t -> consecutive xx
        union { __hip_bfloat16 h[8]; uint4 v; } u;
#pragma unroll
        for (int jj = 0; jj < 8; ++jj) u.h[jj] = __float2bfloat16(lds[xx * 129 + k8 * 8 + jj]);
        *reinterpret_cast<uint4*>(xnt + (((size_t)b * 16 + k8) * 4096 + y * 64 + xx) * 8) = u.v;
    }
    // pool partial: sum over the 64 x's of this row
    const int cin = t & 127, xh = (t >> 7) * 32;
    float s = 0.f;
#pragma unroll
    for (int xx = 0; xx < 32; ++xx) s += lds[(xh + xx) * 129 + cin];
    sred[t] = s;
    __syncthreads();
    if (t < 128) psum[((size_t)b * 64 + y) * CC_CIN + t] = sred[t] + sred[t + 128];
}

// ------------------------------------------------- route: reduce + softmax --
__global__ void cc_route(const float* __restrict__ psum,
                         const float* __restrict__ rw_w,
                         const float* __restrict__ rw_b,
                         float* __restrict__ rweights) {
    const int b = blockIdx.x, c = threadIdx.x;             // 32 blocks x 128
    __shared__ float pl[128];
    __shared__ float lg[8];
    const float* p = psum + (size_t)b * 64 * CC_CIN + c;
    float s = 0.f;
#pragma unroll 8
    for (int y = 0; y < 64; ++y) s += p[(size_t)y * CC_CIN];
    pl[c] = s * (1.f / 4096.f);
    __syncthreads();
    if (c < 8) {
        const float* w = rw_w + c * CC_CIN;
        float a = rw_b[c];
#pragma unroll 8
        for (int i = 0; i < CC_CIN; ++i) a += pl[i] * w[i];
        lg[c] = a;
    }
    __syncthreads();
    if (c == 0) {
        float m = lg[0];
#pragma unroll
        for (int e = 1; e < 8; ++e) m = fmaxf(m, lg[e]);
        float ex[8], sm = 0.f;
#pragma unroll
        for (int e = 0; e < 8; ++e) { ex[e] = __expf(lg[e] - m); sm += ex[e]; }
#pragma unroll
        for (int e = 0; e < 8; ++e) rweights[b * 8 + e] = ex[e] / sm;
    }
}

// -------------------------------------------------------------- combine -----
// cw[b][t9][cout][cin] (bf16) = sum_e rw[b][e] * EW[e][cout][cin][ky][kx]
__global__ void cc_combine(const float* __restrict__ ew,
                           const float* __restrict__ rw,
                           __hip_bfloat16* __restrict__ cw) {
    const int t9 = blockIdx.x >> 8;            // 0..8
    const int cout = blockIdx.x & 255;
    const int cin = threadIdx.x;               // 128 threads
    __shared__ float rws[256];
    rws[cin] = rw[cin];
    rws[cin + 128] = rw[cin + 128];
    __syncthreads();
    float wv[8];
    const size_t base = ((size_t)cout * CC_CIN + cin) * 9 + t9;
#pragma unroll
    for (int e = 0; e < 8; ++e) wv[e] = ew[base + (size_t)e * (CC_COUT * CC_CIN * 9)];
#pragma unroll 4
    for (int b = 0; b < CC_B; ++b) {
        float acc = 0.f;
#pragma unroll
        for (int e = 0; e < 8; ++e) acc += rws[b * 8 + e] * wv[e];
        cw[(((size_t)b * 9 + t9) * CC_COUT + cout) * CC_CIN + cin] = __float2bfloat16(acc);
    }
}

// ----------------------------------------------------------------- conv -----
__device__ __forceinline__ void gload_lds16(const void* g, void* l) {
    __builtin_amdgcn_global_load_lds(
        (const __attribute__((address_space(1))) unsigned int*)g,
        (__attribute__((address_space(3))) unsigned int*)l, 16, 0, 0);
}

// grid 1600, block 256 (4 waves, 2M x 2N). Tile BM=128 couts x BN=160 pos,
// BK=64; per-wave 64x80 (40 MFMA/iter). A: LDS dbuf 2x16KB (swizzled rows);
// B: direct global->VGPR from xnt k-plane layout -- each load = 4 contiguous
// 256B runs (coalesced). bfr double-buffered by unroll parity.
// Iter order: h outer (t<9: h=0), t9 inner -> k8 planes stay hot in L1.
// VM ledger entering iter t: [Astage(t) 4, Bload(t) 10].
//   vmcnt(10) -> A(t) in LDS ; barrier ; Astage(t+1) +4 ; ds_af x8 ;
//   Bload(t+1) +10 ; vmcnt(14) retires B(t) ; lgkm(0) ; 40 MFMA.
// Swizzle: slot s of 128B row r holds source chunk s^(r&7).
__global__ __launch_bounds__(256, 2) void cc_conv(
    const __hip_bfloat16* __restrict__ xnt,  // [B][16][64][64][8]
    const __hip_bfloat16* __restrict__ cw,   // [B][9][256][128]
    float* __restrict__ out)                 // [B][256][3844]
{
    __shared__ __align__(16) char smem[32768];   // A dbuf 2x16KB
    // ---- XCD-aware decode (bijective over 1600 = 8 xcd x 4 b x 25 nt x 2 mt)
    const int l   = blockIdx.x;
    const int xcd = l & 7, li = l >> 3;          // li in [0,200)
    const int b   = 4 * xcd + li / 50;
    const int r2  = li % 50;
    const int nt  = r2 >> 1, mt = r2 & 1;
    const int m0  = mt * 128;
    const int n0  = nt * 160;

    const int tid = threadIdx.x;
    const int wid = tid >> 6, lane = tid & 63;   // wid 0..3
    const int waveM = wid >> 1, waveN = wid & 1;

    f32x4 acc[4][5];
#pragma unroll
    for (int i = 0; i < 4; ++i)
#pragma unroll
        for (int j = 0; j < 5; ++j) acc[i][j] = (f32x4){0.f, 0.f, 0.f, 0.f};

    const int gsw = (lane & 7) ^ (lane >> 3);    // staging source-chunk swizzle
    int laOff[4];
#pragma unroll
    for (int i = 0; i < 4; ++i) {                // A rows: wid*32 + i*8 + l>>3
        const int row = wid * 32 + i * 8 + (lane >> 3);
        laOff[i] = (m0 + row) * CC_CIN + gsw * 8;
    }

    const __hip_bfloat16* cwb = cw + (size_t)b * 9 * CC_COUT * CC_CIN;
    const __hip_bfloat16* xnb = xnt + (size_t)b * 524288;   // 16 planes x 32768

    auto stageA = [&](int t) {
        const int h = t >= 9, t9 = t - 9 * h;
        const int aoff = t9 * (CC_COUT * CC_CIN) + h * 64;
        char* Ab = smem + (t & 1) * 16384 + wid * 4096;
#pragma unroll
        for (int i = 0; i < 4; ++i)
            gload_lds16(cwb + aoff + laOff[i], Ab + i * 1024);
    };

    const int rl = lane & 15, q = lane >> 4;

    // per-lane B pixel offsets (elements in a k8-plane group): q selects plane
    int pixq[5];
#pragma unroll
    for (int nf = 0; nf < 5; ++nf) {
        int p = n0 + waveN * 80 + nf * 16 + rl;
        if (p > CC_NP - 1) p = CC_NP - 1;        // tail clamp (dup, masked at store)
        const int oy = p / 62, ox = p - oy * 62;
        pixq[nf] = q * 32768 + (oy * 64 + ox) * 8;
    }

    bf16x8 bfr[2][10];
    auto loadB = [&](int t) {
        const int h = t >= 9, t9 = t - 9 * h;
        const int ky = (t9 * 11) >> 5;           // t9/3 for t9<9
        const int kx = t9 - ky * 3;
        const int base = h * 262144 + (ky * 64 + kx) * 8;
#pragma unroll
        for (int nf = 0; nf < 5; ++nf)
#pragma unroll
            for (int kk = 0; kk < 2; ++kk)
                bfr[t & 1][nf * 2 + kk] =
                    *(const bf16x8*)(xnb + base + kk * 131072 + pixq[nf]);
    };

    // prologue: establish invariant [A(0) 4, B(0) 10]
    stageA(0);
    loadB(0);

#pragma unroll
    for (int t = 0; t < CC_NT; ++t) {
        const char* Ab = smem + (t & 1) * 16384;

        // ---- A(t) landed in LDS (retire own 4 stage issues), then sync
        asm volatile("s_waitcnt vmcnt(10)" ::: "memory");
        asm volatile("s_barrier" ::: "memory");

        // ---- stage A(t+1) into the other buffer (readers retired last iter)
        if (t + 1 < CC_NT) stageA(t + 1);

        // ---- A fragment reads from LDS
        bf16x8 af[8];
#pragma unroll
        for (int mf = 0; mf < 4; ++mf)
#pragma unroll
            for (int kk = 0; kk < 2; ++kk) {
                const int r = waveM * 64 + mf * 16 + rl;
                af[mf * 2 + kk] = *(const bf16x8*)(Ab + r * 128 + (((kk * 4 + q) ^ (r & 7)) * 16));
            }

        // ---- prefetch B(t+1) into the other register set
        if (t + 1 < CC_NT) loadB(t + 1);

        // ---- B(t) retired (FIFO also covers A(t)); af ready
        if (t < CC_NT - 1) asm volatile("s_waitcnt vmcnt(14)" ::: "memory");
        else               asm volatile("s_waitcnt vmcnt(0)" ::: "memory");
        asm volatile("s_waitcnt lgkmcnt(0)" ::: "memory");

        __builtin_amdgcn_s_setprio(1);
#pragma unroll
        for (int kk = 0; kk < 2; ++kk)
#pragma unroll
            for (int mf = 0; mf < 4; ++mf)
#pragma unroll
                for (int nf = 0; nf < 5; ++nf)
                    acc[mf][nf] = __builtin_amdgcn_mfma_f32_16x16x32_bf16(
                        af[mf * 2 + kk], bfr[t & 1][nf * 2 + kk], acc[mf][nf], 0, 0, 0);
        __builtin_amdgcn_s_setprio(0);
    }

    // epilogue: C/D map col=lane&15 (p), row=(lane>>4)*4+j (cout)
    const int q4 = (lane >> 4) * 4;
#pragma unroll
    for (int mf = 0; mf < 4; ++mf) {
        const int crow = m0 + waveM * 64 + mf * 16 + q4;
#pragma unroll
        for (int nf = 0; nf < 5; ++nf) {
            const int p = n0 + waveN * 80 + nf * 16 + (lane & 15);
            if (p < CC_NP) {
                const size_t ob = ((size_t)b * CC_COUT + crow) * CC_NP + p;
#pragma unroll
                for (int j = 0; j < 4; ++j) out[ob + (size_t)j * CC_NP] = acc[mf][nf][j];
            }
        }
    }
}

// ---------------------------------------------------------------- launch ----
extern "C" void kernel_launch(void* const* d_in, const int* in_sizes, int n_in,
                              void* d_out, int out_size, void* d_ws, size_t ws_size,
                              hipStream_t stream) {
    const float* x   = (const float*)d_in[0];
    const float* ew  = (const float*)d_in[1];
    const float* rww = (const float*)d_in[2];
    const float* rwb = (const float*)d_in[3];
    float* out = (float*)d_out;
    char* ws = (char*)d_ws;

    __hip_bfloat16* xnt   = (__hip_bfloat16*)ws;                    // 33,554,432 B
    __hip_bfloat16* cwcmb = (__hip_bfloat16*)(ws + 33554432);       // 18,874,368 B
    float* psum   = (float*)(ws + 52428800);                        //  1,048,576 B
    float* rwts   = (float*)(ws + 53493760);                        //      1,024 B

    cc_nhwc<<<dim3(CC_B * 64), dim3(256), 0, stream>>>(x, xnt, psum);
    cc_route<<<dim3(CC_B), dim3(128), 0, stream>>>(psum, rww, rwb, rwts);
    cc_combine<<<dim3(9 * CC_COUT), dim3(128), 0, stream>>>(ew, rwts, cwcmb);
    cc_conv<<<dim3(1600), dim3(256), 0, stream>>>(xnt, cwcmb, out);
}

// Round 9
// 118.861 us; speedup vs baseline: 1.6075x; 1.0696x over previous
//
#include <hip/hip_runtime.h>
#include <hip/hip_bf16.h>

// CondConv: B=32, CIN=128, COUT=256, K=3, E=8, H=W=64 -> out [32,256,62,62] fp32
// Pipeline: nhwc(+pool partials) -> route(reduce+softmax) -> combine(bf16 cw)
//           -> implicit-GEMM MFMA conv: block 128x192 (BM+BN=320 = 2-block
//           LDS cap), 4 waves (2Mx2N, per-wave 64x96: 48 MFMA/20 ds_read),
//           2 blocks/CU co-resident, counted vmcnt, full K-unroll.

#define CC_B    32
#define CC_CIN  128
#define CC_COUT 256
#define CC_NP   3844   // 62*62
#define CC_NT   18     // K-tiles: 9 taps x 2 cin-halves of 64

typedef __attribute__((ext_vector_type(8))) short bf16x8;
typedef __attribute__((ext_vector_type(4))) float f32x4;

// ------------------------------------------------- NHWC cast + pool partials
__global__ void cc_nhwc(const float* __restrict__ x, __hip_bfloat16* __restrict__ xn,
                        float* __restrict__ psum) {
    const int b = blockIdx.x >> 6, y = blockIdx.x & 63;   // 2048 blocks
    __shared__ float lds[64 * 129];                        // [x][cin], +1 pad
    __shared__ float sred[256];
    const int t = threadIdx.x;                             // 256
    const float* src = x + (size_t)b * CC_CIN * 4096 + y * 64;
#pragma unroll
    for (int i = 0; i < 32; ++i) {
        const int idx = i * 256 + t;
        const int cin = idx >> 6, xx = idx & 63;
        lds[xx * 129 + cin] = src[(size_t)cin * 4096 + xx];
    }
    __syncthreads();
    __hip_bfloat16* dst = xn + ((size_t)b * 4096 + y * 64) * CC_CIN;
#pragma unroll
    for (int j = 0; j < 4; ++j) {
        const int cidx = j * 256 + t;                      // 1024 chunks of 8 cin
        const int xx = cidx >> 4, c8 = (cidx & 15) * 8;
        union { __hip_bfloat16 h[8]; uint4 v; } u;
#pragma unroll
        for (int jj = 0; jj < 8; ++jj) u.h[jj] = __float2bfloat16(lds[xx * 129 + c8 + jj]);
        *reinterpret_cast<uint4*>(dst + (size_t)xx * CC_CIN + c8) = u.v;
    }
    // pool partial: sum over the 64 x's of this row
    const int cin = t & 127, xh = (t >> 7) * 32;
    float s = 0.f;
#pragma unroll
    for (int xx = 0; xx < 32; ++xx) s += lds[(xh + xx) * 129 + cin];
    sred[t] = s;
    __syncthreads();
    if (t < 128) psum[((size_t)b * 64 + y) * CC_CIN + t] = sred[t] + sred[t + 128];
}

// ------------------------------------------------- route: reduce + softmax --
__global__ void cc_route(const float* __restrict__ psum,
                         const float* __restrict__ rw_w,
                         const float* __restrict__ rw_b,
                         float* __restrict__ rweights) {
    const int b = blockIdx.x, c = threadIdx.x;             // 32 blocks x 128
    __shared__ float pl[128];
    __shared__ float lg[8];
    const float* p = psum + (size_t)b * 64 * CC_CIN + c;
    float s = 0.f;
#pragma unroll 8
    for (int y = 0; y < 64; ++y) s += p[(size_t)y * CC_CIN];
    pl[c] = s * (1.f / 4096.f);
    __syncthreads();
    if (c < 8) {
        const float* w = rw_w + c * CC_CIN;
        float a = rw_b[c];
#pragma unroll 8
        for (int i = 0; i < CC_CIN; ++i) a += pl[i] * w[i];
        lg[c] = a;
    }
    __syncthreads();
    if (c == 0) {
        float m = lg[0];
#pragma unroll
        for (int e = 1; e < 8; ++e) m = fmaxf(m, lg[e]);
        float ex[8], sm = 0.f;
#pragma unroll
        for (int e = 0; e < 8; ++e) { ex[e] = __expf(lg[e] - m); sm += ex[e]; }
#pragma unroll
        for (int e = 0; e < 8; ++e) rweights[b * 8 + e] = ex[e] / sm;
    }
}

// -------------------------------------------------------------- combine -----
// cw[b][t9][cout][cin] (bf16) = sum_e rw[b][e] * EW[e][cout][cin][ky][kx]
__global__ void cc_combine(const float* __restrict__ ew,
                           const float* __restrict__ rw,
                           __hip_bfloat16* __restrict__ cw) {
    const int t9 = blockIdx.x >> 8;            // 0..8
    const int cout = blockIdx.x & 255;
    const int cin = threadIdx.x;               // 128 threads
    __shared__ float rws[256];
    rws[cin] = rw[cin];
    rws[cin + 128] = rw[cin + 128];
    __syncthreads();
    float wv[8];
    const size_t base = ((size_t)cout * CC_CIN + cin) * 9 + t9;
#pragma unroll
    for (int e = 0; e < 8; ++e) wv[e] = ew[base + (size_t)e * (CC_COUT * CC_CIN * 9)];
#pragma unroll 4
    for (int b = 0; b < CC_B; ++b) {
        float acc = 0.f;
#pragma unroll
        for (int e = 0; e < 8; ++e) acc += rws[b * 8 + e] * wv[e];
        cw[(((size_t)b * 9 + t9) * CC_COUT + cout) * CC_CIN + cin] = __float2bfloat16(acc);
    }
}

// ----------------------------------------------------------------- conv -----
__device__ __forceinline__ void gload_lds16(const void* g, void* l) {
    __builtin_amdgcn_global_load_lds(
        (const __attribute__((address_space(1))) unsigned int*)g,
        (__attribute__((address_space(3))) unsigned int*)l, 16, 0, 0);
}

// grid 1344, block 256 (4 waves, 2M x 2N). Tile BM=128 couts x BN=192 pos,
// BK=64; per-wave 64x96 (acc[4][6], 48 MFMA vs 20 ds_read_b128 per iter).
// LDS 80KB: A dbuf 2x16KB @0, B dbuf 2x24KB @32768 -> 2 blocks/CU.
// K-tile t in buf[t&1]; stage(t+2) after close barrier; open = vmcnt(10)
// [stage(t) retired, stage(t+1)'s 10 in flight]. Full unroll (t compile-time).
// Swizzle: slot s of 128B row r holds source chunk s^(r&7) (linear
// global_load_lds dest, pre-swizzled per-lane global source).
__global__ __launch_bounds__(256, 2) void cc_conv(
    const __hip_bfloat16* __restrict__ xn,   // [B][64][64][128]
    const __hip_bfloat16* __restrict__ cw,   // [B][9][256][128]
    float* __restrict__ out)                 // [B][256][3844]
{
    __shared__ __align__(16) char smem[81920];
    // ---- XCD-aware decode (bijective over 1344 = 8 xcd x 4 b x 21 nt x 2 mt)
    const int l   = blockIdx.x;
    const int xcd = l & 7, li = l >> 3;          // li in [0,168)
    const int b   = 4 * xcd + li / 42;
    const int r2  = li % 42;
    const int nt  = r2 >> 1, mt = r2 & 1;
    const int m0  = mt * 128;
    const int n0  = nt * 192;

    const int tid = threadIdx.x;
    const int wid = tid >> 6, lane = tid & 63;   // wid 0..3
    const int waveM = wid >> 1, waveN = wid & 1;

    f32x4 acc[4][6];
#pragma unroll
    for (int i = 0; i < 4; ++i)
#pragma unroll
        for (int j = 0; j < 6; ++j) acc[i][j] = (f32x4){0.f, 0.f, 0.f, 0.f};

    // staging: lane -> row (lane>>3), slot (lane&7); source chunk pre-swizzled
    // so LDS slot s of row r holds chunk s^(r&7)
    const int gsw = (lane & 7) ^ (lane >> 3);
    int laOff[4], lbOff[6];
#pragma unroll
    for (int i = 0; i < 4; ++i) {                // A rows: wid*32 + i*8 + l>>3
        const int row = wid * 32 + i * 8 + (lane >> 3);
        laOff[i] = (m0 + row) * CC_CIN + gsw * 8;
    }
#pragma unroll
    for (int i = 0; i < 6; ++i) {                // B rows: wid*48 + i*8 + l>>3
        const int row = wid * 48 + i * 8 + (lane >> 3);
        int p = n0 + row; if (p > CC_NP - 1) p = CC_NP - 1;   // tail clamp
        const int oy = p / 62, ox = p - oy * 62;
        lbOff[i] = (oy * 64 + ox) * CC_CIN + gsw * 8;
    }

    const __hip_bfloat16* cwb = cw + (size_t)b * 9 * CC_COUT * CC_CIN;
    const __hip_bfloat16* xnb = xn + (size_t)b * 4096 * CC_CIN;

    auto stageK = [&](int t) {
        const int t9 = t >> 1;
        const int ky = (t9 * 11) >> 5;           // t9/3 for t9<9
        const int kx = t9 - ky * 3;
        const int aoff = t9 * (CC_COUT * CC_CIN) + (t & 1) * 64;
        const int boff = (ky * 64 + kx) * CC_CIN + (t & 1) * 64;
        char* Ab = smem + (t & 1) * 16384 + wid * 4096;
        char* Bb = smem + 32768 + (t & 1) * 24576 + wid * 6144;
#pragma unroll
        for (int i = 0; i < 4; ++i)
            gload_lds16(cwb + aoff + laOff[i], Ab + i * 1024);
#pragma unroll
        for (int i = 0; i < 6; ++i)
            gload_lds16(xnb + boff + lbOff[i], Bb + i * 1024);
    };

    const int rl = lane & 15, q = lane >> 4;

    // prologue: 2 K-tiles in flight (20 loads/wave)
    stageK(0);
    stageK(1);

#pragma unroll
    for (int t = 0; t < CC_NT; ++t) {
        const char* Ab = smem + (t & 1) * 16384;
        const char* Bb = smem + 32768 + (t & 1) * 24576;

        // ---- tile open: stage(t) globally visible; stage(t+1) in flight
        if (t < CC_NT - 1) asm volatile("s_waitcnt vmcnt(10)" ::: "memory");
        else               asm volatile("s_waitcnt vmcnt(0)" ::: "memory");
        asm volatile("s_barrier" ::: "memory");

        // ---- frag reads (compiler-scheduled lgkmcnt) + MFMA burst
        bf16x8 af[8], bf[12];
#pragma unroll
        for (int mf = 0; mf < 4; ++mf)
#pragma unroll
            for (int kk = 0; kk < 2; ++kk) {
                const int r = waveM * 64 + mf * 16 + rl;
                af[mf * 2 + kk] = *(const bf16x8*)(Ab + r * 128 + (((kk * 4 + q) ^ (r & 7)) * 16));
            }
#pragma unroll
        for (int nf = 0; nf < 6; ++nf)
#pragma unroll
            for (int kk = 0; kk < 2; ++kk) {
                const int r = waveN * 96 + nf * 16 + rl;
                bf[nf * 2 + kk] = *(const bf16x8*)(Bb + r * 128 + (((kk * 4 + q) ^ (r & 7)) * 16));
            }
        __builtin_amdgcn_s_setprio(1);
#pragma unroll
        for (int kk = 0; kk < 2; ++kk)
#pragma unroll
            for (int mf = 0; mf < 4; ++mf)
#pragma unroll
                for (int nf = 0; nf < 6; ++nf)
                    acc[mf][nf] = __builtin_amdgcn_mfma_f32_16x16x32_bf16(
                        af[mf * 2 + kk], bf[nf * 2 + kk], acc[mf][nf], 0, 0, 0);
        __builtin_amdgcn_s_setprio(0);

        // ---- close: all reads of buf[t&1] done before stage(t+2) overwrites
        asm volatile("s_waitcnt lgkmcnt(0)" ::: "memory");
        asm volatile("s_barrier" ::: "memory");
        if (t + 2 < CC_NT) stageK(t + 2);
    }

    // epilogue: C/D map col=lane&15 (p), row=(lane>>4)*4+j (cout)
    const int q4 = (lane >> 4) * 4;
#pragma unroll
    for (int mf = 0; mf < 4; ++mf) {
        const int crow = m0 + waveM * 64 + mf * 16 + q4;
#pragma unroll
        for (int nf = 0; nf < 6; ++nf) {
            const int p = n0 + waveN * 96 + nf * 16 + (lane & 15);
            if (p < CC_NP) {
                const size_t ob = ((size_t)b * CC_COUT + crow) * CC_NP + p;
#pragma unroll
                for (int j = 0; j < 4; ++j) out[ob + (size_t)j * CC_NP] = acc[mf][nf][j];
            }
        }
    }
}

// ---------------------------------------------------------------- launch ----
extern "C" void kernel_launch(void* const* d_in, const int* in_sizes, int n_in,
                              void* d_out, int out_size, void* d_ws, size_t ws_size,
                              hipStream_t stream) {
    const float* x   = (const float*)d_in[0];
    const float* ew  = (const float*)d_in[1];
    const float* rww = (const float*)d_in[2];
    const float* rwb = (const float*)d_in[3];
    float* out = (float*)d_out;
    char* ws = (char*)d_ws;

    __hip_bfloat16* xnhwc = (__hip_bfloat16*)ws;                    // 33,554,432 B
    __hip_bfloat16* cwcmb = (__hip_bfloat16*)(ws + 33554432);       // 18,874,368 B
    float* psum   = (float*)(ws + 52428800);                        //  1,048,576 B
    float* rwts   = (float*)(ws + 53493760);                        //      1,024 B

    cc_nhwc<<<dim3(CC_B * 64), dim3(256), 0, stream>>>(x, xnhwc, psum);
    cc_route<<<dim3(CC_B), dim3(128), 0, stream>>>(psum, rww, rwb, rwts);
    cc_combine<<<dim3(9 * CC_COUT), dim3(128), 0, stream>>>(ew, rwts, cwcmb);
    cc_conv<<<dim3(1344), dim3(256), 0, stream>>>(xnhwc, cwcmb, out);
}